// Round 8
// baseline (7361.877 us; speedup 1.0000x reference)
//
#include <hip/hip_runtime.h>
#include <stdint.h>

// FPS: B=8, C=3, N=131072, S=2048.
// 32 blocks x 128 threads (2 waves) per batch; 256 blocks total = 1 block/CU
// (no cross-batch co-residency -> minimal phase skew). Cooperative launch.
// Sync: block winner posted to XCD-L2-served volatile slot (one aligned 8B
// atom carrying value|invidx|tag); pipelined 2-deep poll; CAP-spin fallback
// to an agent-scope (IC) array keeps correctness independent of block->XCD
// placement (any block missing a peer caps and republishes; visibility is
// XCD-symmetric -> no hang, graceful degrade). Proven in R7.
// Contiguous ownership: thread owns 32 consecutive indices; slot order ==
// block order == index order -> all ties resolve "lowest lane/slot wins"
// == jnp.argmax first-occurrence. Exact __f*_rn arithmetic,
// (dx*dx+dy*dy)+dz*dz order: trajectory bitwise-identical (absmax 0, R1-R7).

#define BATCHES 8
#define KBLK    32                  // blocks per batch
#define TPB     128                 // 2 waves
#define NWAVE   (TPB / 64)
#define NPTS    131072
#define CHUNK   (NPTS / KBLK)       // 4096 points per block
#define PPT     (CHUNK / TPB)       // 32 points per thread
#define CAP     64                  // fast-poll spins before agent fallback

__global__ __launch_bounds__(TPB) void fps_kernel(
    const float* __restrict__ pts, float* __restrict__ out,
    unsigned long long* __restrict__ ws, int S)
{
    const int gb   = blockIdx.x;            // 0..255
    const int b    = gb & (BATCHES - 1);    // batch (co-XCD heuristic)
    const int blk  = gb >> 3;               // 0..31 within batch
    const int tid  = threadIdx.x;
    const int lane = tid & 63;
    const int wv   = tid >> 6;
    const int myslot = lane & (KBLK - 1);   // lanes 32..63 duplicate slots

    const float* X = pts + (size_t)(b * 3 + 0) * NPTS;
    const float* Y = pts + (size_t)(b * 3 + 1) * NPTS;
    const float* Z = pts + (size_t)(b * 3 + 2) * NPTS;
    float* outb = out + (size_t)b * 3 * S;

    // Contiguous ownership: [base2, base2 + PPT)
    const int base2 = blk * CHUNK + tid * PPT;

    float px[PPT], py[PPT], pz[PPT], md[PPT];
#pragma unroll
    for (int q = 0; q < PPT / 4; ++q) {
        float4 vx = *reinterpret_cast<const float4*>(&X[base2 + 4 * q]);
        float4 vy = *reinterpret_cast<const float4*>(&Y[base2 + 4 * q]);
        float4 vz = *reinterpret_cast<const float4*>(&Z[base2 + 4 * q]);
        px[4*q+0] = vx.x; px[4*q+1] = vx.y; px[4*q+2] = vx.z; px[4*q+3] = vx.w;
        py[4*q+0] = vy.x; py[4*q+1] = vy.y; py[4*q+2] = vy.z; py[4*q+3] = vy.w;
        pz[4*q+0] = vz.x; pz[4*q+1] = vz.y; pz[4*q+2] = vz.z; pz[4*q+3] = vz.w;
    }
#pragma unroll
    for (int k = 0; k < PPT; ++k) md[k] = 1e10f;

    __shared__ unsigned long long s_part[2][NWAVE];

    // ws layout: [par][batch][KBLK] agent, then [par][batch][KBLK] fast.
    unsigned long long* const agnP[2] = {
        ws + (size_t)b * KBLK,
        ws + (size_t)(BATCHES + b) * KBLK };
    volatile unsigned long long* const fstP[2] = {
        (volatile unsigned long long*)(ws + (size_t)(2 * BATCHES + b) * KBLK),
        (volatile unsigned long long*)(ws + (size_t)(3 * BATCHES + b) * KBLK) };

    // Round 0 selection is index 0 (reference).
    float cx = X[0], cy = Y[0], cz = Z[0];
    if (blk == 0 && tid == 0) {
        outb[0]             = cx;
        outb[(size_t)S]     = cy;
        outb[(size_t)2 * S] = cz;
    }

    for (int t = 0; t < S - 1; ++t) {
        // --- update min-dist + thread-local argmax (ascending k, strict >) ---
        float bv = -1.0f;
        int   bk = 0;
#pragma unroll
        for (int k = 0; k < PPT; ++k) {
            float dx = __fsub_rn(px[k], cx);
            float dy = __fsub_rn(py[k], cy);
            float dz = __fsub_rn(pz[k], cz);
            // numpy/jax order: (dx*dx + dy*dy) + dz*dz, no FMA contraction
            float d  = __fadd_rn(__fadd_rn(__fmul_rn(dx, dx), __fmul_rn(dy, dy)),
                                 __fmul_rn(dz, dz));
            float m  = fminf(md[k], d);
            md[k] = m;
            if (m > bv) { bv = m; bk = k; }
        }
        const int bi = base2 + bk;

        // --- wave reduce: fmax butterfly; tie -> lowest lane == lowest idx ---
        float v = bv;
#pragma unroll
        for (int off = 32; off >= 1; off >>= 1)
            v = fmaxf(v, __shfl_xor(v, off));
        unsigned long long eq = __ballot(bv == v);
        int flane = __ffsll(eq) - 1;
        int widx  = __shfl(bi, flane);

        // --- merge the 2 wave partials via parity LDS (one barrier) ---
        const int par = t & 1;
        if (lane == 0)
            s_part[par][wv] =
                ((unsigned long long)__float_as_uint(v) << 32) |
                ((unsigned long long)(unsigned)(0x1FFFF - widx) << 12);
        __syncthreads();
        unsigned long long bp = s_part[par][0];
        unsigned long long o1 = s_part[par][1];
        if (o1 > bp) bp = o1;

        // --- post (fast, XCD-L2) ---
        const unsigned long long tagv = (unsigned long long)(t + 1); // 1..2047
        const unsigned long long mypk = bp | tagv;
        volatile unsigned long long* fst = fstP[par];
        unsigned long long*          agn = agnP[par];
        if (tid == 0) fst[blk] = mypk;

        // --- pipelined poll (2 outstanding); agent fallback after CAP ---
        unsigned long long g;
        {
            int  spins  = 0;
            bool capped = false;
            unsigned long long g0 = fst[myslot];
            for (;;) {
                unsigned long long g1 = fst[myslot];   // in flight while testing g0
                if (capped && (g0 & 0xFFFull) != tagv) {
                    unsigned long long ga = __hip_atomic_load(&agn[myslot],
                        __ATOMIC_RELAXED, __HIP_MEMORY_SCOPE_AGENT);
                    if ((ga & 0xFFFull) == tagv) g0 = ga;
                }
                if (__all((int)((g0 & 0xFFFull) == tagv))) { g = g0; break; }
                unsigned long long g2 = fst[myslot];
                if (capped && (g1 & 0xFFFull) != tagv) {
                    unsigned long long ga = __hip_atomic_load(&agn[myslot],
                        __ATOMIC_RELAXED, __HIP_MEMORY_SCOPE_AGENT);
                    if ((ga & 0xFFFull) == tagv) g1 = ga;
                }
                if (__all((int)((g1 & 0xFFFull) == tagv))) { g = g1; break; }
                g0 = g2;
                spins += 2;
                if (!capped && spins >= CAP) {
                    capped = true;
                    if (tid == 0)
                        __hip_atomic_store(&agn[blk], mypk,
                            __ATOMIC_RELAXED, __HIP_MEMORY_SCOPE_AGENT);
                }
            }
        }

        // --- reduce 32 slot values (replicated over 64 lanes): fmax +
        //     ballot; lowest set lane == lowest slot == lowest index ---
        float gv = __uint_as_float((unsigned)(g >> 32));
        float m2 = gv;
#pragma unroll
        for (int off = 32; off >= 1; off >>= 1)
            m2 = fmaxf(m2, __shfl_xor(m2, off));
        unsigned long long eq2 = __ballot(gv == m2);
        int fl = __ffsll(eq2) - 1;
        unsigned long long win = __shfl(g, fl);

        int far = 0x1FFFF - (int)((win >> 12) & 0x1FFFF);
        far = __builtin_amdgcn_readfirstlane(far);

        // --- next center (uniform scalar loads, L2-hot) + emit ---
        cx = X[far]; cy = Y[far]; cz = Z[far];
        if (blk == 0 && tid == 0) {
            outb[(size_t)(t + 1)]         = cx;
            outb[(size_t)S + (t + 1)]     = cy;
            outb[(size_t)2 * S + (t + 1)] = cz;
        }
    }
}

extern "C" void kernel_launch(void* const* d_in, const int* in_sizes, int n_in,
                              void* d_out, int out_size, void* d_ws, size_t ws_size,
                              hipStream_t stream) {
    const float* pts = (const float*)d_in[0];
    float* out = (float*)d_out;
    unsigned long long* ws = (unsigned long long*)d_ws;
    int S = out_size / (BATCHES * 3);   // 2048

    // Zero all 4 slot arrays (2 parities x {agent, fast}) every replay.
    hipMemsetAsync(d_ws, 0,
                   (size_t)4 * BATCHES * KBLK * sizeof(unsigned long long),
                   stream);

    void* args[] = { (void*)&pts, (void*)&out, (void*)&ws, (void*)&S };
    hipLaunchCooperativeKernel((const void*)fps_kernel,
                               dim3(BATCHES * KBLK), dim3(TPB),
                               args, 0, stream);
}

// Round 9
// 5060.984 us; speedup vs baseline: 1.4546x; 1.4546x over previous
//
#include <hip/hip_runtime.h>
#include <stdint.h>

// FPS: B=8, C=3, N=131072, S=2048.
// R7 structure (proven 3915us): 64 blocks x 64 threads (1 wave) per batch,
// 512 blocks cooperative, batch = blockIdx % 8 (co-XCD heuristic), contiguous
// ownership (thread owns 32 consecutive indices; slot order == block order ==
// index order -> ties = lowest lane/slot = first occurrence == jnp.argmax).
// SINGLE CHANGE vs R7: reducer-broadcast sync. Block 0 of each batch is the
// only poller of the 64 partial slots (8 line-reads/iter vs R7's 512);
// it reduces and broadcasts far|tag to one dedicated cacheline; the other
// 63 blocks poll that single line with s_sleep backoff (1 coalesced
// read/wave/iter) and skip the slot-reduce entirely.
// Correctness independent of placement (G16): posters CAP->publish partials
// to agent-scope slots; reducer CAP->also merges agent slots; reducer always
// mirrors the broadcast agent-scope. Tag (12-bit, unique for S<=2048) rides
// in the same aligned 8B atom as the payload. No hang, graceful degrade.
// Exact __f*_rn arithmetic, (dx*dx+dy*dy)+dz*dz order: trajectory bitwise-
// identical to reference (absmax 0 in R1-R8).

#define BATCHES 8
#define KBLK    64                  // blocks per batch == slots
#define TPB     64
#define NPTS    131072
#define CHUNK   (NPTS / KBLK)       // 2048 points per block
#define PPT     (CHUNK / TPB)       // 32 points per thread
#define CAP     64                  // spins before agent fallback

// ws layout (u64 units):
//   0    : agn_slots[2][8][64]
//   1024 : fst_slots[2][8][64]
//   2048 : fst_bcast[2][8][8]   (8-u64 stride -> one 64B line per batch)
//   2176 : agn_bcast[2][8][8]
//   total 2304 u64 = 18432 B

__global__ __launch_bounds__(TPB) void fps_kernel(
    const float* __restrict__ pts, float* __restrict__ out,
    unsigned long long* __restrict__ ws, int S)
{
    const int gb   = blockIdx.x;            // 0..511
    const int b    = gb & (BATCHES - 1);    // batch (co-XCD heuristic)
    const int blk  = gb >> 3;               // 0..63 within batch
    const int lane = threadIdx.x;           // 0..63

    const float* X = pts + (size_t)(b * 3 + 0) * NPTS;
    const float* Y = pts + (size_t)(b * 3 + 1) * NPTS;
    const float* Z = pts + (size_t)(b * 3 + 2) * NPTS;
    float* outb = out + (size_t)b * 3 * S;

    // Contiguous ownership: [base2, base2 + PPT)
    const int base2 = blk * CHUNK + lane * PPT;

    float px[PPT], py[PPT], pz[PPT], md[PPT];
#pragma unroll
    for (int q = 0; q < PPT / 4; ++q) {
        float4 vx = *reinterpret_cast<const float4*>(&X[base2 + 4 * q]);
        float4 vy = *reinterpret_cast<const float4*>(&Y[base2 + 4 * q]);
        float4 vz = *reinterpret_cast<const float4*>(&Z[base2 + 4 * q]);
        px[4*q+0] = vx.x; px[4*q+1] = vx.y; px[4*q+2] = vx.z; px[4*q+3] = vx.w;
        py[4*q+0] = vy.x; py[4*q+1] = vy.y; py[4*q+2] = vy.z; py[4*q+3] = vy.w;
        pz[4*q+0] = vz.x; pz[4*q+1] = vz.y; pz[4*q+2] = vz.z; pz[4*q+3] = vz.w;
    }
#pragma unroll
    for (int k = 0; k < PPT; ++k) md[k] = 1e10f;

    unsigned long long* const asl[2] = {
        ws + (size_t)b * KBLK,
        ws + 512 + (size_t)b * KBLK };
    volatile unsigned long long* const fsl[2] = {
        (volatile unsigned long long*)(ws + 1024 + (size_t)b * KBLK),
        (volatile unsigned long long*)(ws + 1536 + (size_t)b * KBLK) };
    volatile unsigned long long* const fbc[2] = {
        (volatile unsigned long long*)(ws + 2048 + (size_t)b * 8),
        (volatile unsigned long long*)(ws + 2112 + (size_t)b * 8) };
    unsigned long long* const abc[2] = {
        ws + 2176 + (size_t)b * 8,
        ws + 2240 + (size_t)b * 8 };

    // Round 0 selection is index 0 (reference).
    float cx = X[0], cy = Y[0], cz = Z[0];
    if (blk == 0 && lane == 0) {
        outb[0]             = cx;
        outb[(size_t)S]     = cy;
        outb[(size_t)2 * S] = cz;
    }

    for (int t = 0; t < S - 1; ++t) {
        // --- update min-dist + thread-local argmax (ascending k, strict >) ---
        float bv = -1.0f;
        int   bk = 0;
#pragma unroll
        for (int k = 0; k < PPT; ++k) {
            float dx = __fsub_rn(px[k], cx);
            float dy = __fsub_rn(py[k], cy);
            float dz = __fsub_rn(pz[k], cz);
            // numpy/jax order: (dx*dx + dy*dy) + dz*dz, no FMA contraction
            float d  = __fadd_rn(__fadd_rn(__fmul_rn(dx, dx), __fmul_rn(dy, dy)),
                                 __fmul_rn(dz, dz));
            float m  = fminf(md[k], d);
            md[k] = m;
            if (m > bv) { bv = m; bk = k; }
        }
        const int bi = base2 + bk;

        // --- wave reduce: fmax butterfly; tie -> lowest lane == lowest idx ---
        float v = bv;
#pragma unroll
        for (int off = 32; off >= 1; off >>= 1)
            v = fmaxf(v, __shfl_xor(v, off));
        unsigned long long eq = __ballot(bv == v);
        int flane = __ffsll(eq) - 1;
        int widx  = __shfl(bi, flane);

        const int par = t & 1;
        const unsigned long long tagv = (unsigned long long)(t + 1); // 1..2047
        const unsigned long long mypk =
            ((unsigned long long)__float_as_uint(v) << 32) |
            ((unsigned long long)(unsigned)(0x1FFFF - widx) << 12) | tagv;

        // --- post partial (fast, XCD-L2) ---
        if (lane == 0) fsl[par][blk] = mypk;

        int far;
        if (blk == 0) {
            // ---- reducer: sole poller of the 64 slots (8 lines/iter) ----
            unsigned long long g;
            {
                int  spins  = 0;
                bool capped = false;
                for (;;) {
                    unsigned long long gf = fsl[par][lane];
                    bool ok = ((gf & 0xFFFull) == tagv);
                    if (capped && !ok) {
                        unsigned long long ga = __hip_atomic_load(&asl[par][lane],
                            __ATOMIC_RELAXED, __HIP_MEMORY_SCOPE_AGENT);
                        if ((ga & 0xFFFull) == tagv) { gf = ga; ok = true; }
                    }
                    g = gf;
                    if (__all((int)ok)) break;
                    if (!capped && ++spins == CAP) capped = true;
                }
            }
            // reduce 64 partials: fmax + ballot; lowest lane = lowest slot
            // = lowest index (first occurrence)
            float gv = __uint_as_float((unsigned)(g >> 32));
            float m2 = gv;
#pragma unroll
            for (int off = 32; off >= 1; off >>= 1)
                m2 = fmaxf(m2, __shfl_xor(m2, off));
            unsigned long long eq2 = __ballot(gv == m2);
            int fl = __ffsll(eq2) - 1;
            unsigned long long win = __shfl(g, fl);
            far = 0x1FFFF - (int)((win >> 12) & 0x1FFFF);

            // broadcast far|tag (fast line + agent mirror)
            if (lane == 0) {
                unsigned long long w =
                    ((unsigned long long)(unsigned)far << 12) | tagv;
                fbc[par][0] = w;
                __hip_atomic_store(&abc[par][0], w,
                                   __ATOMIC_RELAXED, __HIP_MEMORY_SCOPE_AGENT);
            }
        } else {
            // ---- poller: one coalesced read of the bcast line per iter ----
            int  spins  = 0;
            bool capped = false;
            for (;;) {
                unsigned long long w = fbc[par][0];
                if ((w & 0xFFFull) == tagv) {
                    far = (int)((w >> 12) & 0x1FFFF);
                    break;
                }
                if (capped) {
                    unsigned long long wa = __hip_atomic_load(&abc[par][0],
                        __ATOMIC_RELAXED, __HIP_MEMORY_SCOPE_AGENT);
                    if ((wa & 0xFFFull) == tagv) {
                        far = (int)((wa >> 12) & 0x1FFFF);
                        break;
                    }
                }
                if (!capped && ++spins == CAP) {
                    capped = true;
                    if (lane == 0)
                        __hip_atomic_store(&asl[par][blk], mypk,
                            __ATOMIC_RELAXED, __HIP_MEMORY_SCOPE_AGENT);
                }
                __builtin_amdgcn_s_sleep(1);  // backoff: cut bcast-line storm
            }
        }
        far = __builtin_amdgcn_readfirstlane(far);

        // --- next center (uniform scalar loads, L2-hot) + emit ---
        cx = X[far]; cy = Y[far]; cz = Z[far];
        if (blk == 0 && lane == 0) {
            outb[(size_t)(t + 1)]         = cx;
            outb[(size_t)S + (t + 1)]     = cy;
            outb[(size_t)2 * S + (t + 1)] = cz;
        }
    }
}

extern "C" void kernel_launch(void* const* d_in, const int* in_sizes, int n_in,
                              void* d_out, int out_size, void* d_ws, size_t ws_size,
                              hipStream_t stream) {
    const float* pts = (const float*)d_in[0];
    float* out = (float*)d_out;
    unsigned long long* ws = (unsigned long long*)d_ws;
    int S = out_size / (BATCHES * 3);   // 2048

    // Zero all slot + bcast arrays every replay (captured in the graph).
    hipMemsetAsync(d_ws, 0, (size_t)2304 * sizeof(unsigned long long), stream);

    void* args[] = { (void*)&pts, (void*)&out, (void*)&ws, (void*)&S };
    hipLaunchCooperativeKernel((const void*)fps_kernel,
                               dim3(BATCHES * KBLK), dim3(TPB),
                               args, 0, stream);
}

// Round 10
// 3754.078 us; speedup vs baseline: 1.9610x; 1.3481x over previous
//
#include <hip/hip_runtime.h>
#include <stdint.h>

// FPS: B=8, C=3, N=131072, S=2048.
// R7 structure (proven 3915us): 64 blocks x 64 threads (1 wave) per batch,
// 512 blocks cooperative, batch = blockIdx % 8 (co-XCD heuristic), contiguous
// ownership (thread owns 32 consecutive indices; slot order == block order ==
// index order -> ties = lowest lane/slot = first occurrence == jnp.argmax).
// Flat symmetric sync (R9's reducer-broadcast regressed): every wave polls
// all 64 slots (lane i watches slot i), fmax+ballot reduce, XCD-L2 volatile
// fast path + agent-scope CAP fallback (correct under any block->XCD
// placement; no hang, graceful degrade).
// R10 changes vs R7:
//  (1) __launch_bounds__(64,1): point arrays in true VGPRs (R7's 76-VGPR
//      count proves they were in AGPRs -> ~160 accvgpr moves/round).
//  (2) Tail overlap: per-lane speculative gather of own-slot candidate's
//      coords issued BEFORE the slot-reduce butterfly; winner coords arrive
//      via 3 shfl. Removes serial readfirstlane -> s_load gather.
// Exact __f*_rn arithmetic, (dx*dx+dy*dy)+dz*dz order: trajectory bitwise-
// identical to reference (absmax 0 in R1-R9).

#define BATCHES 8
#define KBLK    64                  // blocks per batch == slots == lanes
#define TPB     64
#define NPTS    131072
#define CHUNK   (NPTS / KBLK)       // 2048 points per block
#define PPT     (CHUNK / TPB)       // 32 points per thread
#define CAP     64                  // fast-poll spins before agent fallback

__global__ __launch_bounds__(TPB, 1) void fps_kernel(
    const float* __restrict__ pts, float* __restrict__ out,
    unsigned long long* __restrict__ ws, int S)
{
    const int gb   = blockIdx.x;            // 0..511
    const int b    = gb & (BATCHES - 1);    // batch (co-XCD heuristic)
    const int blk  = gb >> 3;               // 0..63 within batch
    const int lane = threadIdx.x;           // 0..63

    const float* X = pts + (size_t)(b * 3 + 0) * NPTS;
    const float* Y = pts + (size_t)(b * 3 + 1) * NPTS;
    const float* Z = pts + (size_t)(b * 3 + 2) * NPTS;
    float* outb = out + (size_t)b * 3 * S;

    // Contiguous ownership: [base2, base2 + PPT)
    const int base2 = blk * CHUNK + lane * PPT;

    float px[PPT], py[PPT], pz[PPT], md[PPT];
#pragma unroll
    for (int q = 0; q < PPT / 4; ++q) {
        float4 vx = *reinterpret_cast<const float4*>(&X[base2 + 4 * q]);
        float4 vy = *reinterpret_cast<const float4*>(&Y[base2 + 4 * q]);
        float4 vz = *reinterpret_cast<const float4*>(&Z[base2 + 4 * q]);
        px[4*q+0] = vx.x; px[4*q+1] = vx.y; px[4*q+2] = vx.z; px[4*q+3] = vx.w;
        py[4*q+0] = vy.x; py[4*q+1] = vy.y; py[4*q+2] = vy.z; py[4*q+3] = vy.w;
        pz[4*q+0] = vz.x; pz[4*q+1] = vz.y; pz[4*q+2] = vz.z; pz[4*q+3] = vz.w;
    }
#pragma unroll
    for (int k = 0; k < PPT; ++k) md[k] = 1e10f;

    // Slot arrays: [parity][batch][KBLK]; agent (IC) backstop + fast (L2).
    unsigned long long* const agnP[2] = {
        ws + (size_t)b * KBLK,
        ws + (size_t)(BATCHES + b) * KBLK };
    volatile unsigned long long* const fstP[2] = {
        (volatile unsigned long long*)(ws + (size_t)(2 * BATCHES + b) * KBLK),
        (volatile unsigned long long*)(ws + (size_t)(3 * BATCHES + b) * KBLK) };

    // Round 0 selection is index 0 (reference).
    float cx = X[0], cy = Y[0], cz = Z[0];
    if (blk == 0 && lane == 0) {
        outb[0]             = cx;
        outb[(size_t)S]     = cy;
        outb[(size_t)2 * S] = cz;
    }

    for (int t = 0; t < S - 1; ++t) {
        // --- update min-dist + thread-local argmax (ascending k, strict >) ---
        float bv = -1.0f;
        int   bk = 0;
#pragma unroll
        for (int k = 0; k < PPT; ++k) {
            float dx = __fsub_rn(px[k], cx);
            float dy = __fsub_rn(py[k], cy);
            float dz = __fsub_rn(pz[k], cz);
            // numpy/jax order: (dx*dx + dy*dy) + dz*dz, no FMA contraction
            float d  = __fadd_rn(__fadd_rn(__fmul_rn(dx, dx), __fmul_rn(dy, dy)),
                                 __fmul_rn(dz, dz));
            float m  = fminf(md[k], d);
            md[k] = m;
            if (m > bv) { bv = m; bk = k; }
        }
        const int bi = base2 + bk;

        // --- wave reduce: fmax butterfly; tie -> lowest lane == lowest idx ---
        float v = bv;
#pragma unroll
        for (int off = 32; off >= 1; off >>= 1)
            v = fmaxf(v, __shfl_xor(v, off));
        unsigned long long eq = __ballot(bv == v);
        int   flane = __ffsll(eq) - 1;
        int   widx  = __shfl(bi, flane);

        const unsigned long long tagv = (unsigned long long)(t + 1); // 1..2047
        const unsigned long long mypk =
            ((unsigned long long)__float_as_uint(v) << 32) |
            ((unsigned long long)(unsigned)(0x1FFFF - widx) << 12) | tagv;

        volatile unsigned long long* fst = fstP[t & 1];
        unsigned long long*          agn = agnP[t & 1];

        // --- post (fast, XCD-L2) ---
        if (lane == 0) fst[blk] = mypk;

        // --- poll: lane i watches slot i; agent fallback after CAP spins ---
        unsigned long long g;
        {
            int  spins  = 0;
            bool capped = false;
            for (;;) {
                unsigned long long gf = fst[lane];
                bool ok = ((gf & 0xFFFull) == tagv);
                if (capped && !ok) {
                    unsigned long long ga = __hip_atomic_load(&agn[lane],
                        __ATOMIC_RELAXED, __HIP_MEMORY_SCOPE_AGENT);
                    if ((ga & 0xFFFull) == tagv) { gf = ga; ok = true; }
                }
                g = gf;
                if (__all((int)ok)) break;
                if (!capped && ++spins == CAP) {
                    capped = true;
                    if (lane == 0)
                        __hip_atomic_store(&agn[blk], mypk,
                            __ATOMIC_RELAXED, __HIP_MEMORY_SCOPE_AGENT);
                }
            }
        }

        // --- tail overlap: speculative per-lane gather of own-slot
        //     candidate's coords (L2-hit latency hides under butterfly) ---
        const int cand = 0x1FFFF - (int)((g >> 12) & 0x1FFFF);
        float gx = X[cand];
        float gy = Y[cand];
        float gz = Z[cand];

        // --- reduce 64 slot values: fmax butterfly + ballot; slot order ==
        //     block order == index order -> lowest lane = first occurrence ---
        float gv = __uint_as_float((unsigned)(g >> 32));
        float m2 = gv;
#pragma unroll
        for (int off = 32; off >= 1; off >>= 1)
            m2 = fmaxf(m2, __shfl_xor(m2, off));
        unsigned long long eq2 = __ballot(gv == m2);
        int fl = __ffsll(eq2) - 1;

        // --- winner's coords via shfl (no serial scalar gather) ---
        cx = __shfl(gx, fl);
        cy = __shfl(gy, fl);
        cz = __shfl(gz, fl);
        if (blk == 0 && lane == 0) {
            outb[(size_t)(t + 1)]         = cx;
            outb[(size_t)S + (t + 1)]     = cy;
            outb[(size_t)2 * S + (t + 1)] = cz;
        }
    }
}

extern "C" void kernel_launch(void* const* d_in, const int* in_sizes, int n_in,
                              void* d_out, int out_size, void* d_ws, size_t ws_size,
                              hipStream_t stream) {
    const float* pts = (const float*)d_in[0];
    float* out = (float*)d_out;
    unsigned long long* ws = (unsigned long long*)d_ws;
    int S = out_size / (BATCHES * 3);   // 2048

    // Zero all 4 slot arrays (2 parities x {agent, fast}) every replay.
    hipMemsetAsync(d_ws, 0,
                   (size_t)4 * BATCHES * KBLK * sizeof(unsigned long long),
                   stream);

    void* args[] = { (void*)&pts, (void*)&out, (void*)&ws, (void*)&S };
    hipLaunchCooperativeKernel((const void*)fps_kernel,
                               dim3(BATCHES * KBLK), dim3(TPB),
                               args, 0, stream);
}